// Round 1
// baseline (9.639 us; speedup 1.0000x reference)
//
#include <hip/hip_runtime.h>
#include <math.h>

// QAOA reference, fully reduced:
//   N=4 qubits, D=1, H=6 terms, S=14 states.
//   GRAY[s] = s ^ (s>>1)  (binary-reflected Gray code bit pattern).
//   Only 2x2 diagonals matter (base has zero off-diagonals), so
//   trace(h,s,n) = 0.5 * sh1 * sh2 * fb1 * fb2 * (1 + b11(h,n)*z1(n)*z2(n))
//   with sh = prod_j (hfl_j ? -i sin(theta_j) : cos(theta_j)),
//        fb = xflag ? 0 : cos(beta0)    (PX has zero diagonal),
//        z(n) = (-1)^{# j : hfl_j & flags[j][n]},  b11 = flags[h][n] ? -1 : +1.
//   result = sum_{h,s} w[h] * prod_n trace(h,s,n)   (complex scalar).
// Computed in fp64 (values are ~1e-9 products of many trig factors; threshold
// is 2% absolute of that, fp64 keeps us ~100x under it).

#define NQ 4
#define NH 6
#define NS 14

struct cplx { double re, im; };
__device__ __forceinline__ cplx cmul(cplx a, cplx b) {
    return { a.re * b.re - a.im * b.im, a.re * b.im + a.im * b.re };
}
__device__ __forceinline__ cplx cscale(cplx a, double s) {
    return { a.re * s, a.im * s };
}

__global__ void qaoa_kernel(const float* __restrict__ w,      // [H]
                            const int*   __restrict__ flags,  // [H][N] 0/1
                            const float* __restrict__ beta,   // [D]
                            const float* __restrict__ gamma,  // [D]
                            float* __restrict__ out, int out_size)
{
    __shared__ double s_re[128];
    __shared__ double s_im[128];
    const int tid = threadIdx.x;

    // Shared trig precompute (every thread does it; trivial cost)
    const double cb = cos((double)beta[0]);
    const double g0 = (double)gamma[0];
    double cth[NH], sth[NH];
#pragma unroll
    for (int j = 0; j < NH; ++j) {
        double th = g0 * (double)w[j];
        cth[j] = cos(th);
        sth[j] = sin(th);
    }

    double re = 0.0, im = 0.0;
    if (tid < NH * NS) {
        const int h = tid / NS;
        const int s = tid % NS;
        const unsigned g = (unsigned)s ^ ((unsigned)s >> 1);

        // half 1: offset 0 -> xflag = bit 0, hfl = bits 1..6
        const unsigned x1   = g & 1u;
        const unsigned hfl1 = (g >> 1) & 0x3Fu;
        // half 2: offset 7 -> xflag = bit 7, hfl = bits 8..13
        const unsigned x2   = (g >> 7) & 1u;
        const unsigned hfl2 = (g >> 8) & 0x3Fu;

        cplx sh1 = {1.0, 0.0}, sh2 = {1.0, 0.0};
#pragma unroll
        for (int j = 0; j < NH; ++j) {
            cplx c1 = ((hfl1 >> j) & 1u) ? cplx{0.0, -sth[j]} : cplx{cth[j], 0.0};
            cplx c2 = ((hfl2 >> j) & 1u) ? cplx{0.0, -sth[j]} : cplx{cth[j], 0.0};
            sh1 = cmul(sh1, c1);
            sh2 = cmul(sh2, c2);
        }

        const double fb1 = x1 ? 0.0 : cb;   // PX diagonal is zero
        const double fb2 = x2 ? 0.0 : cb;
        const cplx  s12  = cmul(sh1, sh2);
        const double fbb = 0.5 * fb1 * fb2;

        cplx temp = {1.0, 0.0};
#pragma unroll
        for (int n = 0; n < NQ; ++n) {
            int cnt1 = 0, cnt2 = 0;
#pragma unroll
            for (int j = 0; j < NH; ++j) {
                const int f = (flags[j * NQ + n] != 0) ? 1 : 0;
                cnt1 += (int)((hfl1 >> j) & 1u) & f;
                cnt2 += (int)((hfl2 >> j) & 1u) & f;
            }
            const double z1  = (cnt1 & 1) ? -1.0 : 1.0;
            const double z2  = (cnt2 & 1) ? -1.0 : 1.0;
            const double b11 = (flags[h * NQ + n] != 0) ? -1.0 : 1.0;
            const double scal = fbb * (1.0 + b11 * z1 * z2);
            const cplx tr = cscale(s12, scal);
            temp = cmul(temp, tr);
        }
        const double wh = (double)w[h];
        re = wh * temp.re;
        im = wh * temp.im;
    }

    s_re[tid] = re;
    s_im[tid] = im;
    __syncthreads();
#pragma unroll
    for (int off = 64; off > 0; off >>= 1) {
        if (tid < off) {
            s_re[tid] += s_re[tid + off];
            s_im[tid] += s_im[tid + off];
        }
        __syncthreads();
    }
    if (tid == 0) {
        if (out_size > 0) out[0] = (float)s_re[0];
        if (out_size > 1) out[1] = (float)s_im[0];
    }
}

extern "C" void kernel_launch(void* const* d_in, const int* in_sizes, int n_in,
                              void* d_out, int out_size, void* d_ws, size_t ws_size,
                              hipStream_t stream) {
    const float* w     = (const float*)d_in[0];
    const int*   flags = (const int*)d_in[1];
    const float* beta  = (const float*)d_in[2];
    const float* gamma = (const float*)d_in[3];
    float* out = (float*)d_out;
    (void)in_sizes; (void)n_in; (void)d_ws; (void)ws_size;
    qaoa_kernel<<<1, 128, 0, stream>>>(w, flags, beta, gamma, out, out_size);
}

// Round 2
// 9.571 us; speedup vs baseline: 1.0071x; 1.0071x over previous
//
#include <hip/hip_runtime.h>
#include <math.h>

// QAOA reference, fully reduced (see round-0 derivation):
//   N=4 qubits, D=1, H=6 terms, S=14 states; GRAY[s] = s ^ (s>>1).
//   trace(h,s,n) = 0.5 * sh1*sh2 * fb1*fb2 * (1 + b11(h,n)*z1(n)*z2(n))
//   result = sum_{h,s} w[h] * prod_n trace(h,s,n).
// fp32 throughout: threshold is 2% relative; fp32 chain error ~1e-6 relative.
// Single 64-lane wave, 2 items/lane, shuffle reduction (no LDS, no barriers).

#define NQ 4
#define NH 6
#define NS 14
#define NITEMS (NH * NS)   // 84

struct cplxf { float re, im; };
__device__ __forceinline__ cplxf cmulf(cplxf a, cplxf b) {
    return { a.re * b.re - a.im * b.im, a.re * b.im + a.im * b.re };
}

__device__ __forceinline__ void accum_item(int item,
                                           const float* cth, const float* sth,
                                           float cb, const int* fl, const float* wl,
                                           float& re, float& im)
{
    const int h = item / NS;
    const int s = item % NS;
    const unsigned g = (unsigned)s ^ ((unsigned)s >> 1);

    const unsigned x1   = g & 1u;            // half 1: offset 0
    const unsigned hfl1 = (g >> 1) & 0x3Fu;
    const unsigned x2   = (g >> 7) & 1u;     // half 2: offset 7
    const unsigned hfl2 = (g >> 8) & 0x3Fu;

    cplxf sh1 = {1.f, 0.f}, sh2 = {1.f, 0.f};
#pragma unroll
    for (int j = 0; j < NH; ++j) {
        cplxf c1 = ((hfl1 >> j) & 1u) ? cplxf{0.f, -sth[j]} : cplxf{cth[j], 0.f};
        cplxf c2 = ((hfl2 >> j) & 1u) ? cplxf{0.f, -sth[j]} : cplxf{cth[j], 0.f};
        sh1 = cmulf(sh1, c1);
        sh2 = cmulf(sh2, c2);
    }

    const float fb1 = x1 ? 0.f : cb;   // PX diagonal is zero
    const float fb2 = x2 ? 0.f : cb;
    const cplxf s12 = cmulf(sh1, sh2);
    const float fbb = 0.5f * fb1 * fb2;

    cplxf temp = {1.f, 0.f};
#pragma unroll
    for (int n = 0; n < NQ; ++n) {
        int cnt1 = 0, cnt2 = 0;
#pragma unroll
        for (int j = 0; j < NH; ++j) {
            const int f = fl[j * NQ + n];
            cnt1 += (int)((hfl1 >> j) & 1u) & f;
            cnt2 += (int)((hfl2 >> j) & 1u) & f;
        }
        const float z12 = ((cnt1 ^ cnt2) & 1) ? -1.f : 1.f;  // z1*z2
        const float b11 = fl[h * NQ + n] ? -1.f : 1.f;
        const float scal = fbb * (1.f + b11 * z12);
        temp = cmulf(temp, cplxf{s12.re * scal, s12.im * scal});
    }
    re += wl[h] * temp.re;
    im += wl[h] * temp.im;
}

__global__ void qaoa_kernel(const float* __restrict__ w,      // [H]
                            const int*   __restrict__ flags,  // [H][N] 0/1
                            const float* __restrict__ beta,   // [D]
                            const float* __restrict__ gamma,  // [D]
                            float* __restrict__ out, int out_size)
{
    const int lane = threadIdx.x;

    // Per-lane precompute (trivial; avoids any cross-lane dependency)
    const float cb = cosf(beta[0]);
    const float g0 = gamma[0];
    float cth[NH], sth[NH], wl[NH];
    int fl[NH * NQ];
#pragma unroll
    for (int j = 0; j < NH; ++j) {
        wl[j] = w[j];
        __sincosf(g0 * wl[j], &sth[j], &cth[j]);
        // refine with accurate versions (negligible cost, keeps margin huge)
        sth[j] = sinf(g0 * wl[j]);
        cth[j] = cosf(g0 * wl[j]);
    }
#pragma unroll
    for (int k = 0; k < NH * NQ; ++k) fl[k] = (flags[k] != 0) ? 1 : 0;

    float re = 0.f, im = 0.f;
    accum_item(lane, cth, sth, cb, fl, wl, re, im);          // items 0..63
    if (lane < NITEMS - 64)
        accum_item(lane + 64, cth, sth, cb, fl, wl, re, im); // items 64..83

    // Wave-64 shuffle reduction
#pragma unroll
    for (int off = 32; off > 0; off >>= 1) {
        re += __shfl_down(re, off, 64);
        im += __shfl_down(im, off, 64);
    }
    if (lane == 0) {
        if (out_size > 0) out[0] = re;
        if (out_size > 1) out[1] = im;
    }
}

extern "C" void kernel_launch(void* const* d_in, const int* in_sizes, int n_in,
                              void* d_out, int out_size, void* d_ws, size_t ws_size,
                              hipStream_t stream) {
    const float* w     = (const float*)d_in[0];
    const int*   flags = (const int*)d_in[1];
    const float* beta  = (const float*)d_in[2];
    const float* gamma = (const float*)d_in[3];
    float* out = (float*)d_out;
    (void)in_sizes; (void)n_in; (void)d_ws; (void)ws_size;
    qaoa_kernel<<<1, 64, 0, stream>>>(w, flags, beta, gamma, out, out_size);
}